// Round 17
// baseline (141.217 us; speedup 1.0000x reference)
//
#include <hip/hip_runtime.h>
#include <cstdint>

#define B_  4
#define S_  4096
#define DIN 1024
#define DH  128
// attention scale with log2(e) folded in: scores come out in log2 domain
#define QSCALE (0.08838834764831845f * 1.4426950408889634f)

typedef short bf16x8 __attribute__((ext_vector_type(8)));
typedef float f32x4 __attribute__((ext_vector_type(4)));
typedef unsigned short u16;
typedef unsigned int   u32;

#define MFMA16(a, b, c) __builtin_amdgcn_mfma_f32_16x16x32_bf16(a, b, c, 0, 0, 0)

#define GLOAD_LDS16(g, l) __builtin_amdgcn_global_load_lds( \
    (const __attribute__((address_space(1))) void*)(g),     \
    (__attribute__((address_space(3))) void*)(l), 16, 0, 0)

#if __has_builtin(__builtin_amdgcn_exp2f)
#define EXP2(x) __builtin_amdgcn_exp2f(x)
#else
#define EXP2(x) exp2f(x)
#endif

__device__ inline u16 bf16_rn(float f) {
    union { float f; u32 u; } v; v.f = f;
    u32 r = v.u + 0x7FFFu + ((v.u >> 16) & 1u);
    return (u16)(r >> 16);
}
__device__ inline float bf16_f(u16 h) {
    union { u32 u; float f; } v; v.u = ((u32)h) << 16; return v.f;
}
// packed bf16(a) | bf16(b)<<16 via HW cvt (RNE)
__device__ inline u32 pk2(float a, float b) {
    u32 r;
    asm("v_cvt_pk_bf16_f32 %0, %1, %2" : "=v"(r) : "v"(a), "v"(b));
    return r;
}
__device__ inline void split2(float a, float b, u32& hi, u32& lo) {
    u32 ua = __builtin_bit_cast(u32, a), ub = __builtin_bit_cast(u32, b);
    u32 ha = ua & 0xFFFF0000u, hb = ub & 0xFFFF0000u;
    hi = (ua >> 16) | hb;
    float la = a - __builtin_bit_cast(float, ha);
    float lb = b - __builtin_bit_cast(float, hb);
    lo = (u32)bf16_rn(la) | ((u32)bf16_rn(lb) << 16);
}

// ---------------- Kernel 0: wconv2 (unchanged) ----------------
__global__ __launch_bounds__(256) void wconv2(
    const float* __restrict__ Wq, const float* __restrict__ Wk, const float* __restrict__ Wv,
    u16* __restrict__ wpack)
{
    int id  = blockIdx.x * 256 + threadIdx.x;   // 0..81919
    int s   = id / 2560;
    int rem = id % 2560;
    int p   = rem >> 9;
    int gi  = rem & 511;
    int n   = gi & 127, kq2 = gi >> 7;
    const float* W = (p < 2) ? Wq : (p < 4) ? Wk : Wv;
    int k0 = 32 * s + 8 * kq2;
    u16 o[8];
    #pragma unroll
    for (int j = 0; j < 8; ++j) {
        float v = W[(size_t)(k0 + j) * DH + n];
        if (p < 2) v *= QSCALE;
        if (p == 4) {
            o[j] = bf16_rn(v);
        } else {
            u32 u = __builtin_bit_cast(u32, v);
            if ((p & 1) == 0) o[j] = (u16)(u >> 16);
            else o[j] = bf16_rn(v - __builtin_bit_cast(float, u & 0xFFFF0000u));
        }
    }
    u16* dst = wpack + (size_t)id * 8;
    *(uint4*)dst = *(uint4*)o;
}

// ---------------- Kernel 1: fused QKV v8 (unchanged from round 13) ----------------
__global__ __launch_bounds__(512) void qkv_v8(
    const float* __restrict__ x, const u16* __restrict__ wpack,
    u16* __restrict__ qhi, u16* __restrict__ qlo,
    u16* __restrict__ khi, u16* __restrict__ klo, u16* __restrict__ vt)
{
    __shared__ __align__(16) char lds[81920];   // 2 bufs x 40960

    const int t    = threadIdx.x;
    const int row0 = blockIdx.x * 64;
    const int lane = t & 63, wave = t >> 6;
    const int l15  = lane & 15, g = lane >> 4;
    const int wr   = wave >> 1;
    const int wc   = wave & 1;

    f32x4 accq[4], acck[4], accv[4];
    #pragma unroll
    for (int nt = 0; nt < 4; ++nt)
        #pragma unroll
        for (int r = 0; r < 4; ++r) {
            accq[nt][r] = 0.f; acck[nt][r] = 0.f; accv[nt][r] = 0.f;
        }

    const char* WP = (const char*)wpack;
    auto stage = [&](int bufi, int s) {
        char* d = lds + bufi * 40960;
        const char* src = WP + (size_t)s * 40960;
        #pragma unroll
        for (int c = 0; c < 5; ++c) {
            int o = t * 16 + c * 8192;
            GLOAD_LDS16(src + o, d + o);
        }
    };

    const float* xp = x + (size_t)(row0 + 16 * wr + l15) * DIN + 8 * g;

    float4 ca = *(const float4*)(xp);
    float4 cb = *(const float4*)(xp + 4);

    stage(0, 0);
    __syncthreads();

    int buf = 0;
    for (int s = 0; s < 32; ++s) {
        if (s < 31) stage(buf ^ 1, s + 1);

        float4 na, nb;
        if (s < 31) {
            na = *(const float4*)(xp + 32 * (s + 1));
            nb = *(const float4*)(xp + 32 * (s + 1) + 4);
        }

        bf16x8 xh, xl;
        {
            uint4 H, L;
            split2(ca.x, ca.y, H.x, L.x); split2(ca.z, ca.w, H.y, L.y);
            split2(cb.x, cb.y, H.z, L.z); split2(cb.z, cb.w, H.w, L.w);
            xh = __builtin_bit_cast(bf16x8, H);
            xl = __builtin_bit_cast(bf16x8, L);
        }

        const char* wb = lds + buf * 40960;
        #pragma unroll
        for (int nt = 0; nt < 4; ++nt) {
            const int n  = 64 * wc + 16 * nt + l15;
            const int wo = (g << 11) + (n << 4);
            bf16x8 qwh = *(const bf16x8*)(wb + wo);
            bf16x8 qwl = *(const bf16x8*)(wb +  8192 + wo);
            bf16x8 kwh = *(const bf16x8*)(wb + 16384 + wo);
            bf16x8 kwl = *(const bf16x8*)(wb + 24576 + wo);
            bf16x8 vwh = *(const bf16x8*)(wb + 32768 + wo);
            accq[nt] = MFMA16(xh, qwh, accq[nt]);
            accq[nt] = MFMA16(xl, qwh, accq[nt]);
            accq[nt] = MFMA16(xh, qwl, accq[nt]);
            acck[nt] = MFMA16(xh, kwh, acck[nt]);
            acck[nt] = MFMA16(xl, kwh, acck[nt]);
            acck[nt] = MFMA16(xh, kwl, acck[nt]);
            accv[nt] = MFMA16(xh, vwh, accv[nt]);
        }
        __syncthreads();
        if (s < 31) { ca = na; cb = nb; }
        buf ^= 1;
    }

    const int bb = row0 >> 12, kt = (row0 & 4095) >> 6;

    #pragma unroll
    for (int reg = 0; reg < 4; ++reg) {
        int r = row0 + 16 * wr + 4 * g + reg;
        #pragma unroll
        for (int nt = 0; nt < 4; ++nt) {
            int c = 64 * wc + 16 * nt + l15;
            float v = accq[nt][reg];
            u32 u = __builtin_bit_cast(u32, v);
            float lo = v - __builtin_bit_cast(float, u & 0xFFFF0000u);
            size_t o = (size_t)r * DH + c;
            qhi[o] = (u16)(u >> 16);
            qlo[o] = bf16_rn(lo);
        }
    }

    u16* lk = (u16*)lds;
    #pragma unroll
    for (int reg = 0; reg < 4; ++reg) {
        int kr = 16 * wr + 4 * g + reg;
        #pragma unroll
        for (int nt = 0; nt < 4; ++nt) {
            int c = 64 * wc + 16 * nt + l15;
            int o = kr * 128 + (((c >> 3) ^ (kr & 15)) << 3) + (c & 7);
            float v = acck[nt][reg];
            u32 u = __builtin_bit_cast(u32, v);
            lk[o]        = (u16)(u >> 16);
            lk[8192 + o] = bf16_rn(v - __builtin_bit_cast(float, u & 0xFFFF0000u));
        }
    }
    __syncthreads();
    {
        char* gk = (char*)(khi + (size_t)(bb * 64 + kt) * 8192);
        char* gl = (char*)(klo + (size_t)(bb * 64 + kt) * 8192);
        #pragma unroll
        for (int c2 = 0; c2 < 2; ++c2) {
            int o = t * 16 + c2 * 8192;
            *(uint4*)(gk + o) = *(const uint4*)(lds + o);
            *(uint4*)(gl + o) = *(const uint4*)(lds + 16384 + o);
        }
    }
    __syncthreads();

    #pragma unroll
    for (int reg = 0; reg < 4; ++reg) {
        int kr = 16 * wr + 4 * g + reg;
        #pragma unroll
        for (int nt = 0; nt < 4; ++nt) {
            int c = 64 * wc + 16 * nt + l15;
            int o = c * 64 + (((kr >> 3) ^ (c & 7)) << 3) + (kr & 7);
            lk[o] = bf16_rn(accv[nt][reg]);
        }
    }
    __syncthreads();
    {
        char* gv = (char*)(vt + (size_t)(bb * 64 + kt) * 8192);
        #pragma unroll
        for (int c2 = 0; c2 < 2; ++c2) {
            int o = t * 16 + c2 * 8192;
            *(uint4*)(gv + o) = *(const uint4*)(lds + o);
        }
    }
}

// ---------------- Kernel 2: flash_p — 2-tile software pipeline, 3-buffer rotation ----------------
// Per tile: stage(t+2) -> QK(t+1) [MFMA] -> softmax(t) [VALU] -> PV(t) [MFMA] -> barrier.
// All lane algebra identical to the r10-r16-verified flash_db; only re-sequenced.
__global__ __launch_bounds__(512, 2) void flash_p(
    const u16* __restrict__ qhi, const u16* __restrict__ qlo,
    const u16* __restrict__ khi, const u16* __restrict__ klo,
    const u16* __restrict__ vt,
    u16* __restrict__ opart, float2* __restrict__ ml)
{
    __shared__ __align__(16) char smem[3 * 49152];

    const int tid  = threadIdx.x;
    const int wave = tid >> 6, lane = tid & 63;
    const int l15  = lane & 15, g = lane >> 4;
    const int bid  = blockIdx.x;
    const int pair = bid & 15, qt = bid >> 4;   // pair%8 spreads (b,z) across XCDs
    const int b = pair >> 2, z = pair & 3;

    const int q0row = b * S_ + qt * 256 + wave * 32;

    bf16x8 qh[2][4], ql[2][4];
    #pragma unroll
    for (int h = 0; h < 2; ++h)
        #pragma unroll
        for (int ks = 0; ks < 4; ++ks) {
            size_t qa = (size_t)(q0row + 16 * h + l15) * DH + 32 * ks + 8 * g;
            qh[h][ks] = *(const bf16x8*)(qhi + qa);
            ql[h][ks] = *(const bf16x8*)(qlo + qa);
        }

    f32x4 O0[8], O1[8];
    #pragma unroll
    for (int dt = 0; dt < 8; ++dt)
        #pragma unroll
        for (int r = 0; r < 4; ++r) { O0[dt][r] = 0.f; O1[dt][r] = 0.f; }

    float m0 = -3.0e38f, l0 = 0.f, m1 = -3.0e38f, l1 = 0.f;

    int koff[4];
    #pragma unroll
    for (int ks = 0; ks < 4; ++ks)
        koff[ks] = (((4 * ks + g) ^ l15) << 4) + (l15 << 8);
    int voff[2];
    #pragma unroll
    for (int kw = 0; kw < 2; ++kw)
        voff[kw] = (((4 * kw + g) ^ (l15 & 7)) << 4);

    const char* kbase = (const char*)(khi + (size_t)b * 64 * 8192);
    const char* lbase = (const char*)(klo + (size_t)b * 64 * 8192);
    const char* vbase = (const char*)(vt  + (size_t)b * 64 * 8192);
    const int kt0 = z * 16;

    auto stage = [&](char* dk, int ktl) {
        const char* sk = kbase + (size_t)(kt0 + ktl) * 16384;
        const char* sl = lbase + (size_t)(kt0 + ktl) * 16384;
        const char* sv = vbase + (size_t)(kt0 + ktl) * 16384;
        #pragma unroll
        for (int c = 0; c < 2; ++c) {
            int o = tid * 16 + c * 8192;
            GLOAD_LDS16(sk + o, dk + o);
            GLOAD_LDS16(sl + o, dk + 16384 + o);
            GLOAD_LDS16(sv + o, dk + 32768 + o);
        }
    };

    // QK^T for one tile: scores into (s0,s1) from K at bk (hi) / bk+16K (lo)
    auto qk = [&](f32x4* s0, f32x4* s1, const char* bk) {
        const char* bl = bk + 16384;
        #pragma unroll
        for (int nt = 0; nt < 4; ++nt)
            #pragma unroll
            for (int r = 0; r < 4; ++r) { s0[nt][r] = 0.f; s1[nt][r] = 0.f; }
        __builtin_amdgcn_s_setprio(1);
        #pragma unroll
        for (int ks = 0; ks < 4; ++ks) {
            #pragma unroll
            for (int nt = 0; nt < 4; ++nt) {
                bf16x8 kh = *(const bf16x8*)(bk + nt * 4096 + koff[ks]);
                bf16x8 kl = *(const bf16x8*)(bl + nt * 4096 + koff[ks]);
                s0[nt] = MFMA16(kh, qh[0][ks], s0[nt]);
                s0[nt] = MFMA16(kh, ql[0][ks], s0[nt]);
                s0[nt] = MFMA16(kl, qh[0][ks], s0[nt]);
                s1[nt] = MFMA16(kh, qh[1][ks], s1[nt]);
                s1[nt] = MFMA16(kh, ql[1][ks], s1[nt]);
                s1[nt] = MFMA16(kl, qh[1][ks], s1[nt]);
            }
        }
        __builtin_amdgcn_s_setprio(0);
    };

    // softmax + PV for one tile: consumes (s0,s1), V from bv
    auto smpv = [&](f32x4* s0, f32x4* s1, const char* bv) {
        float ml0 = -3.0e38f, ml1 = -3.0e38f;
        #pragma unroll
        for (int nt = 0; nt < 4; ++nt)
            #pragma unroll
            for (int r = 0; r < 4; ++r) {
                ml0 = fmaxf(ml0, s0[nt][r]);
                ml1 = fmaxf(ml1, s1[nt][r]);
            }
        ml0 = fmaxf(ml0, __shfl_xor(ml0, 16));
        ml0 = fmaxf(ml0, __shfl_xor(ml0, 32));
        ml1 = fmaxf(ml1, __shfl_xor(ml1, 16));
        ml1 = fmaxf(ml1, __shfl_xor(ml1, 32));

        if (!__all((ml0 <= m0 + 8.0f) & (ml1 <= m1 + 8.0f))) {
            float mn0 = fmaxf(m0, ml0), mn1 = fmaxf(m1, ml1);
            float fsc0 = EXP2(m0 - mn0), fsc1 = EXP2(m1 - mn1);
            m0 = mn0; m1 = mn1;
            l0 *= fsc0; l1 *= fsc1;
            float fr0[4], fr1[4];
            #pragma unroll
            for (int r = 0; r < 4; ++r) {
                fr0[r] = __shfl(fsc0, 4 * g + r);
                fr1[r] = __shfl(fsc1, 4 * g + r);
            }
            #pragma unroll
            for (int dt = 0; dt < 8; ++dt)
                #pragma unroll
                for (int r = 0; r < 4; ++r) {
                    O0[dt][r] *= fr0[r];
                    O1[dt][r] *= fr1[r];
                }
        }

        u32 pk0[4][2], pk1[4][2];
        float ps0 = 0.f, ps1 = 0.f;
        #pragma unroll
        for (int nt = 0; nt < 4; ++nt) {
            float a0 = EXP2(s0[nt][0] - m0), a1 = EXP2(s0[nt][1] - m0);
            float a2 = EXP2(s0[nt][2] - m0), a3 = EXP2(s0[nt][3] - m0);
            ps0 += (a0 + a1) + (a2 + a3);
            pk0[nt][0] = pk2(a0, a1);
            pk0[nt][1] = pk2(a2, a3);
            float c0 = EXP2(s1[nt][0] - m1), c1 = EXP2(s1[nt][1] - m1);
            float c2 = EXP2(s1[nt][2] - m1), c3 = EXP2(s1[nt][3] - m1);
            ps1 += (c0 + c1) + (c2 + c3);
            pk1[nt][0] = pk2(c0, c1);
            pk1[nt][1] = pk2(c2, c3);
        }
        ps0 += __shfl_xor(ps0, 16);
        ps0 += __shfl_xor(ps0, 32);
        ps1 += __shfl_xor(ps1, 16);
        ps1 += __shfl_xor(ps1, 32);
        l0 += ps0; l1 += ps1;

        const int s0l = l15 | ((2 * (g & 1)) << 4);
        const int s1l = s0l + 16;
        const int hiH = g >> 1;
        #pragma unroll
        for (int kw = 0; kw < 2; ++kw) {
            u32 a0, a1, a2, a3, c0, c1, c2, c3;
            {
                u32 x0 = __shfl(pk0[2 * kw][0], s0l), y0 = __shfl(pk0[2 * kw + 1][0], s0l);
                u32 x1 = __shfl(pk0[2 * kw][1], s0l), y1 = __shfl(pk0[2 * kw + 1][1], s0l);
                u32 x2 = __shfl(pk0[2 * kw][0], s1l), y2 = __shfl(pk0[2 * kw + 1][0], s1l);
                u32 x3 = __shfl(pk0[2 * kw][1], s1l), y3 = __shfl(pk0[2 * kw + 1][1], s1l);
                a0 = hiH ? y0 : x0; a1 = hiH ? y1 : x1;
                a2 = hiH ? y2 : x2; a3 = hiH ? y3 : x3;
            }
            {
                u32 x0 = __shfl(pk1[2 * kw][0], s0l), y0 = __shfl(pk1[2 * kw + 1][0], s0l);
                u32 x1 = __shfl(pk1[2 * kw][1], s0l), y1 = __shfl(pk1[2 * kw + 1][1], s0l);
                u32 x2 = __shfl(pk1[2 * kw][0], s1l), y2 = __shfl(pk1[2 * kw + 1][0], s1l);
                u32 x3 = __shfl(pk1[2 * kw][1], s1l), y3 = __shfl(pk1[2 * kw + 1][1], s1l);
                c0 = hiH ? y0 : x0; c1 = hiH ? y1 : x1;
                c2 = hiH ? y2 : x2; c3 = hiH ? y3 : x3;
            }
            union { u32 w[4]; bf16x8 v; } pa, pb;
            pa.w[0] = a0; pa.w[1] = a1; pa.w[2] = a2; pa.w[3] = a3;
            pb.w[0] = c0; pb.w[1] = c1; pb.w[2] = c2; pb.w[3] = c3;
            __builtin_amdgcn_s_setprio(1);
            #pragma unroll
            for (int dt = 0; dt < 8; ++dt) {
                bf16x8 vf = *(const bf16x8*)(bv + (16 * dt + l15) * 128 + voff[kw]);
                O0[dt] = MFMA16(pa.v, vf, O0[dt]);
                O1[dt] = MFMA16(pb.v, vf, O1[dt]);
            }
            __builtin_amdgcn_s_setprio(0);
        }
    };

    // ---- prologue: stage tiles 0,1; compute scores of tile 0 ----
    char* pc = smem;                 // holds tile t
    char* pn = smem + 49152;         // holds tile t+1
    char* pf = smem + 2 * 49152;     // staging dest for tile t+2
    stage(pc, 0);
    stage(pn, 1);
    __syncthreads();

    f32x4 sE0[4], sE1[4], sO0[4], sO1[4];
    qk(sE0, sE1, pc);                // tile 0 scores

    for (int tt = 0; tt < 8; ++tt) {
        // ---- even tile t = 2*tt (scores in E; next into O) ----
        if (tt < 7) stage(pf, 2 * tt + 2);
        qk(sO0, sO1, pn);                        // tile 2tt+1
        smpv(sE0, sE1, pc + 32768);              // tile 2tt
        __syncthreads();
        { char* tmp = pc; pc = pn; pn = pf; pf = tmp; }

        // ---- odd tile t = 2*tt+1 (scores in O; next into E) ----
        if (tt < 7) {
            stage(pf, 2 * tt + 3);
            qk(sE0, sE1, pn);                    // tile 2tt+2
        }
        smpv(sO0, sO1, pc + 32768);              // tile 2tt+1
        __syncthreads();
        { char* tmp = pc; pc = pn; pn = pf; pf = tmp; }
    }

    // ---- epilogue: bf16 unnormalized partials + (m,l); m is log2-domain ----
    u16* op = opart + ((size_t)z * 16384 + q0row) * DH;
    #pragma unroll
    for (int dt = 0; dt < 8; ++dt)
        #pragma unroll
        for (int r = 0; r < 4; ++r) {
            op[(size_t)(4 * g + r) * DH + 16 * dt + l15]      = bf16_rn(O0[dt][r]);
            op[(size_t)(16 + 4 * g + r) * DH + 16 * dt + l15] = bf16_rn(O1[dt][r]);
        }
    if (lane < 16) {
        ml[(size_t)z * 16384 + q0row + lane]      = make_float2(m0, l0);
        ml[(size_t)z * 16384 + q0row + 16 + lane] = make_float2(m1, l1);
    }
}

// ---------------- Kernel 3: merge the 4 kt-partials (unchanged) ----------------
__global__ __launch_bounds__(256) void merge4(
    const u16* __restrict__ op, const float2* __restrict__ ml, float* __restrict__ O)
{
    int row = blockIdx.x * 16 + (threadIdx.x >> 4);
    int dq  = (threadIdx.x & 15) * 8;
    float2 a[4];
    #pragma unroll
    for (int zz = 0; zz < 4; ++zz) a[zz] = ml[(size_t)zz * 16384 + row];
    float M = fmaxf(fmaxf(a[0].x, a[1].x), fmaxf(a[2].x, a[3].x));
    float w[4], den = 0.f;
    #pragma unroll
    for (int zz = 0; zz < 4; ++zz) {
        w[zz] = EXP2(a[zz].x - M);
        den += a[zz].y * w[zz];
    }
    float inv = 1.0f / den;
    float acc[8];
    #pragma unroll
    for (int j = 0; j < 8; ++j) acc[j] = 0.f;
    #pragma unroll
    for (int zz = 0; zz < 4; ++zz) {
        const u16* p = op + ((size_t)zz * 16384 + row) * DH + dq;
        bf16x8 vv = *(const bf16x8*)p;
        #pragma unroll
        for (int j = 0; j < 8; ++j) acc[j] += w[zz] * bf16_f((u16)vv[j]);
    }
    float4 oa, ob;
    oa.x = acc[0] * inv; oa.y = acc[1] * inv; oa.z = acc[2] * inv; oa.w = acc[3] * inv;
    ob.x = acc[4] * inv; ob.y = acc[5] * inv; ob.z = acc[6] * inv; ob.w = acc[7] * inv;
    *(float4*)(O + (size_t)row * DH + dq)     = oa;
    *(float4*)(O + (size_t)row * DH + dq + 4) = ob;
}

extern "C" void kernel_launch(void* const* d_in, const int* in_sizes, int n_in,
                              void* d_out, int out_size, void* d_ws, size_t ws_size,
                              hipStream_t stream) {
    const float* x  = (const float*)d_in[0];
    const float* Wq = (const float*)d_in[1];
    const float* Wk = (const float*)d_in[2];
    const float* Wv = (const float*)d_in[3];
    float* out = (float*)d_out;

    const size_t SZ = (size_t)B_ * S_ * DH;     // 2,097,152 elems (4 MiB bf16 each)
    u16* qhi = (u16*)d_ws;
    u16* qlo = qhi + SZ;
    u16* khi = qlo + SZ;
    u16* klo = khi + SZ;
    u16* vtp = klo + SZ;
    u16* wpk = vtp + SZ;                        // 1.25 MiB staging image
    u16* opart = wpk + 655360;                  // 16 MiB bf16 partials (Z=4)
    float2* mlp = (float2*)((char*)opart + (size_t)4 * 16384 * DH * 2);
    // total = 20.97M + 1.31M + 16.78M + 0.52M = 39.58 MB (proven bound)

    wconv2<<<320, 256, 0, stream>>>(Wq, Wk, Wv, wpk);
    qkv_v8<<<256, 512, 0, stream>>>(x, wpk, qhi, qlo, khi, klo, vtp);
    flash_p<<<256, 512, 0, stream>>>(qhi, qlo, khi, klo, vtp, opart, mlp);
    merge4<<<1024, 256, 0, stream>>>(opart, mlp, out);
}

// Round 18
// 126.619 us; speedup vs baseline: 1.1153x; 1.1153x over previous
//
#include <hip/hip_runtime.h>
#include <cstdint>

#define B_  4
#define S_  4096
#define DIN 1024
#define DH  128
// attention scale with log2(e) folded in: scores come out in log2 domain
#define QSCALE (0.08838834764831845f * 1.4426950408889634f)

typedef short bf16x8 __attribute__((ext_vector_type(8)));
typedef float f32x4 __attribute__((ext_vector_type(4)));
typedef unsigned short u16;
typedef unsigned int   u32;

#define MFMA16(a, b, c) __builtin_amdgcn_mfma_f32_16x16x32_bf16(a, b, c, 0, 0, 0)

#define GLOAD_LDS16(g, l) __builtin_amdgcn_global_load_lds( \
    (const __attribute__((address_space(1))) void*)(g),     \
    (__attribute__((address_space(3))) void*)(l), 16, 0, 0)

#if __has_builtin(__builtin_amdgcn_exp2f)
#define EXP2(x) __builtin_amdgcn_exp2f(x)
#else
#define EXP2(x) exp2f(x)
#endif

__device__ inline u16 bf16_rn(float f) {
    union { float f; u32 u; } v; v.f = f;
    u32 r = v.u + 0x7FFFu + ((v.u >> 16) & 1u);
    return (u16)(r >> 16);
}
__device__ inline float bf16_f(u16 h) {
    union { u32 u; float f; } v; v.u = ((u32)h) << 16; return v.f;
}
// packed bf16(a) | bf16(b)<<16 via HW cvt (RNE, bit-identical to bf16_rn on finite vals)
__device__ inline u32 pk2(float a, float b) {
    u32 r;
    asm("v_cvt_pk_bf16_f32 %0, %1, %2" : "=v"(r) : "v"(a), "v"(b));
    return r;
}
__device__ inline void split2(float a, float b, u32& hi, u32& lo) {
    u32 ua = __builtin_bit_cast(u32, a), ub = __builtin_bit_cast(u32, b);
    u32 ha = ua & 0xFFFF0000u, hb = ub & 0xFFFF0000u;
    hi = (ua >> 16) | hb;
    float la = a - __builtin_bit_cast(float, ha);
    float lb = b - __builtin_bit_cast(float, hb);
    lo = (u32)bf16_rn(la) | ((u32)bf16_rn(lb) << 16);
}

// ---------------- Kernel 0: wconv2 — emit the exact staging image ----------------
// wpack[s(32)][p(5)][gi(512)] of 16B granules; gi = kq2*128 + n;
// granule holds W'[32s + 8*kq2 + j][n], j=0..7.  p: 0=Qhi 1=Qlo 2=Khi 3=Klo 4=Vrn.
__global__ __launch_bounds__(256) void wconv2(
    const float* __restrict__ Wq, const float* __restrict__ Wk, const float* __restrict__ Wv,
    u16* __restrict__ wpack)
{
    int id  = blockIdx.x * 256 + threadIdx.x;   // 0..81919
    int s   = id / 2560;
    int rem = id % 2560;
    int p   = rem >> 9;
    int gi  = rem & 511;
    int n   = gi & 127, kq2 = gi >> 7;
    const float* W = (p < 2) ? Wq : (p < 4) ? Wk : Wv;
    int k0 = 32 * s + 8 * kq2;
    u16 o[8];
    #pragma unroll
    for (int j = 0; j < 8; ++j) {
        float v = W[(size_t)(k0 + j) * DH + n];
        if (p < 2) v *= QSCALE;
        if (p == 4) {
            o[j] = bf16_rn(v);                       // V: round-to-nearest
        } else {
            u32 u = __builtin_bit_cast(u32, v);
            if ((p & 1) == 0) o[j] = (u16)(u >> 16); // hi: trunc
            else o[j] = bf16_rn(v - __builtin_bit_cast(float, u & 0xFFFF0000u));
        }
    }
    u16* dst = wpack + (size_t)id * 8;
    *(uint4*)dst = *(uint4*)o;
}

// ---------------- Kernel 1: fused QKV v8 (round-13-verified) ----------------
__global__ __launch_bounds__(512) void qkv_v8(
    const float* __restrict__ x, const u16* __restrict__ wpack,
    u16* __restrict__ qhi, u16* __restrict__ qlo,
    u16* __restrict__ khi, u16* __restrict__ klo, u16* __restrict__ vt)
{
    __shared__ __align__(16) char lds[81920];   // 2 bufs x 40960

    const int t    = threadIdx.x;
    const int row0 = blockIdx.x * 64;
    const int lane = t & 63, wave = t >> 6;
    const int l15  = lane & 15, g = lane >> 4;
    const int wr   = wave >> 1;                 // 0..3: 16-row group
    const int wc   = wave & 1;                  // 0..1: 64-col group

    f32x4 accq[4], acck[4], accv[4];
    #pragma unroll
    for (int nt = 0; nt < 4; ++nt)
        #pragma unroll
        for (int r = 0; r < 4; ++r) {
            accq[nt][r] = 0.f; acck[nt][r] = 0.f; accv[nt][r] = 0.f;
        }

    const char* WP = (const char*)wpack;
    auto stage = [&](int bufi, int s) {
        char* d = lds + bufi * 40960;
        const char* src = WP + (size_t)s * 40960;
        #pragma unroll
        for (int c = 0; c < 5; ++c) {
            int o = t * 16 + c * 8192;
            GLOAD_LDS16(src + o, d + o);
        }
    };

    const float* xp = x + (size_t)(row0 + 16 * wr + l15) * DIN + 8 * g;

    // x for step 0
    float4 ca = *(const float4*)(xp);
    float4 cb = *(const float4*)(xp + 4);

    stage(0, 0);
    __syncthreads();

    int buf = 0;
    for (int s = 0; s < 32; ++s) {
        if (s < 31) stage(buf ^ 1, s + 1);

        float4 na, nb;
        if (s < 31) {
            na = *(const float4*)(xp + 32 * (s + 1));
            nb = *(const float4*)(xp + 32 * (s + 1) + 4);
        }

        bf16x8 xh, xl;
        {
            uint4 H, L;
            split2(ca.x, ca.y, H.x, L.x); split2(ca.z, ca.w, H.y, L.y);
            split2(cb.x, cb.y, H.z, L.z); split2(cb.z, cb.w, H.w, L.w);
            xh = __builtin_bit_cast(bf16x8, H);
            xl = __builtin_bit_cast(bf16x8, L);
        }

        const char* wb = lds + buf * 40960;
        #pragma unroll
        for (int nt = 0; nt < 4; ++nt) {
            const int n  = 64 * wc + 16 * nt + l15;
            const int wo = (g << 11) + (n << 4);
            bf16x8 qwh = *(const bf16x8*)(wb + wo);
            bf16x8 qwl = *(const bf16x8*)(wb +  8192 + wo);
            bf16x8 kwh = *(const bf16x8*)(wb + 16384 + wo);
            bf16x8 kwl = *(const bf16x8*)(wb + 24576 + wo);
            bf16x8 vwh = *(const bf16x8*)(wb + 32768 + wo);
            accq[nt] = MFMA16(xh, qwh, accq[nt]);
            accq[nt] = MFMA16(xl, qwh, accq[nt]);
            accq[nt] = MFMA16(xh, qwl, accq[nt]);
            acck[nt] = MFMA16(xh, kwh, acck[nt]);
            acck[nt] = MFMA16(xl, kwh, acck[nt]);
            acck[nt] = MFMA16(xh, kwl, acck[nt]);
            accv[nt] = MFMA16(xh, vwh, accv[nt]);
        }
        __syncthreads();
        if (s < 31) { ca = na; cb = nb; }
        buf ^= 1;
    }

    // ---- epilogue: r12-verified imaging formulas, 8-wave indexing ----
    const int bb = row0 >> 12, kt = (row0 & 4095) >> 6;

    // Q: direct stores (lane-coalesced)
    #pragma unroll
    for (int reg = 0; reg < 4; ++reg) {
        int r = row0 + 16 * wr + 4 * g + reg;
        #pragma unroll
        for (int nt = 0; nt < 4; ++nt) {
            int c = 64 * wc + 16 * nt + l15;
            float v = accq[nt][reg];
            u32 u = __builtin_bit_cast(u32, v);
            float lo = v - __builtin_bit_cast(float, u & 0xFFFF0000u);
            size_t o = (size_t)r * DH + c;
            qhi[o] = (u16)(u >> 16);
            qlo[o] = bf16_rn(lo);
        }
    }

    // K: build 16KB khi + 16KB klo tile images in LDS, coalesced copy out.
    u16* lk = (u16*)lds;
    #pragma unroll
    for (int reg = 0; reg < 4; ++reg) {
        int kr = 16 * wr + 4 * g + reg;
        #pragma unroll
        for (int nt = 0; nt < 4; ++nt) {
            int c = 64 * wc + 16 * nt + l15;
            int o = kr * 128 + (((c >> 3) ^ (kr & 15)) << 3) + (c & 7);
            float v = acck[nt][reg];
            u32 u = __builtin_bit_cast(u32, v);
            lk[o]        = (u16)(u >> 16);
            lk[8192 + o] = bf16_rn(v - __builtin_bit_cast(float, u & 0xFFFF0000u));
        }
    }
    __syncthreads();
    {
        char* gk = (char*)(khi + (size_t)(bb * 64 + kt) * 8192);
        char* gl = (char*)(klo + (size_t)(bb * 64 + kt) * 8192);
        #pragma unroll
        for (int c2 = 0; c2 < 2; ++c2) {
            int o = t * 16 + c2 * 8192;
            *(uint4*)(gk + o) = *(const uint4*)(lds + o);
            *(uint4*)(gl + o) = *(const uint4*)(lds + 16384 + o);
        }
    }
    __syncthreads();

    // V: build 16KB vt tile image in LDS, coalesced copy out.
    #pragma unroll
    for (int reg = 0; reg < 4; ++reg) {
        int kr = 16 * wr + 4 * g + reg;
        #pragma unroll
        for (int nt = 0; nt < 4; ++nt) {
            int c = 64 * wc + 16 * nt + l15;
            int o = c * 64 + (((kr >> 3) ^ (c & 7)) << 3) + (kr & 7);
            lk[o] = bf16_rn(accv[nt][reg]);
        }
    }
    __syncthreads();
    {
        char* gv = (char*)(vt + (size_t)(bb * 64 + kt) * 8192);
        #pragma unroll
        for (int c2 = 0; c2 < 2; ++c2) {
            int o = t * 16 + c2 * 8192;
            *(uint4*)(gv + o) = *(const uint4*)(lds + o);
        }
    }
}

// ---------------- Kernel 2: flash attention, double-buffered, Z=4 ----------------
// r10-r13-verified flash_db body + cvt_pk pk2 + setprio around MFMA clusters (r16).
__global__ __launch_bounds__(512, 2) void flash_db(
    const u16* __restrict__ qhi, const u16* __restrict__ qlo,
    const u16* __restrict__ khi, const u16* __restrict__ klo,
    const u16* __restrict__ vt,
    u16* __restrict__ opart, float2* __restrict__ ml)
{
    __shared__ __align__(16) char smem[2 * 49152];

    const int tid  = threadIdx.x;
    const int wave = tid >> 6, lane = tid & 63;
    const int l15  = lane & 15, g = lane >> 4;
    const int bid  = blockIdx.x;
    const int pair = bid & 15, qt = bid >> 4;   // pair%8 spreads (b,z) across XCDs
    const int b = pair >> 2, z = pair & 3;

    const int q0row = b * S_ + qt * 256 + wave * 32;

    bf16x8 qh[2][4], ql[2][4];
    #pragma unroll
    for (int h = 0; h < 2; ++h)
        #pragma unroll
        for (int ks = 0; ks < 4; ++ks) {
            size_t qa = (size_t)(q0row + 16 * h + l15) * DH + 32 * ks + 8 * g;
            qh[h][ks] = *(const bf16x8*)(qhi + qa);
            ql[h][ks] = *(const bf16x8*)(qlo + qa);
        }

    f32x4 O0[8], O1[8];
    #pragma unroll
    for (int dt = 0; dt < 8; ++dt)
        #pragma unroll
        for (int r = 0; r < 4; ++r) { O0[dt][r] = 0.f; O1[dt][r] = 0.f; }

    float m0 = -3.0e38f, l0 = 0.f, m1 = -3.0e38f, l1 = 0.f;

    int koff[4];
    #pragma unroll
    for (int ks = 0; ks < 4; ++ks)
        koff[ks] = (((4 * ks + g) ^ l15) << 4) + (l15 << 8);
    int voff[2];
    #pragma unroll
    for (int kw = 0; kw < 2; ++kw)
        voff[kw] = (((4 * kw + g) ^ (l15 & 7)) << 4);

    const char* kbase = (const char*)(khi + (size_t)b * 64 * 8192);
    const char* lbase = (const char*)(klo + (size_t)b * 64 * 8192);
    const char* vbase = (const char*)(vt  + (size_t)b * 64 * 8192);
    const int kt0 = z * 16;

    auto stage = [&](int bufi, int ktl) {
        const char* sk = kbase + (size_t)(kt0 + ktl) * 16384;
        const char* sl = lbase + (size_t)(kt0 + ktl) * 16384;
        const char* sv = vbase + (size_t)(kt0 + ktl) * 16384;
        char* dk = smem + bufi * 49152;
        #pragma unroll
        for (int c = 0; c < 2; ++c) {
            int o = tid * 16 + c * 8192;
            GLOAD_LDS16(sk + o, dk + o);
            GLOAD_LDS16(sl + o, dk + 16384 + o);
            GLOAD_LDS16(sv + o, dk + 32768 + o);
        }
    };

    stage(0, 0);
    __syncthreads();

    int buf = 0;
    for (int ktl = 0; ktl < 16; ++ktl) {
        if (ktl < 15) stage(buf ^ 1, ktl + 1);

        const char* bk = smem + buf * 49152;
        const char* bl = bk + 16384;
        const char* bv = bk + 32768;

        f32x4 s0[4], s1[4];
        #pragma unroll
        for (int nt = 0; nt < 4; ++nt)
            #pragma unroll
            for (int r = 0; r < 4; ++r) { s0[nt][r] = 0.f; s1[nt][r] = 0.f; }

        __builtin_amdgcn_s_setprio(1);
        #pragma unroll
        for (int ks = 0; ks < 4; ++ks) {
            #pragma unroll
            for (int nt = 0; nt < 4; ++nt) {
                bf16x8 kh = *(const bf16x8*)(bk + nt * 4096 + koff[ks]);
                bf16x8 kl = *(const bf16x8*)(bl + nt * 4096 + koff[ks]);
                s0[nt] = MFMA16(kh, qh[0][ks], s0[nt]);
                s0[nt] = MFMA16(kh, ql[0][ks], s0[nt]);
                s0[nt] = MFMA16(kl, qh[0][ks], s0[nt]);
                s1[nt] = MFMA16(kh, qh[1][ks], s1[nt]);
                s1[nt] = MFMA16(kh, ql[1][ks], s1[nt]);
                s1[nt] = MFMA16(kl, qh[1][ks], s1[nt]);
            }
        }
        __builtin_amdgcn_s_setprio(0);

        // ---- tile maxima (log2 domain) ----
        float ml0 = -3.0e38f, ml1 = -3.0e38f;
        #pragma unroll
        for (int nt = 0; nt < 4; ++nt)
            #pragma unroll
            for (int r = 0; r < 4; ++r) {
                ml0 = fmaxf(ml0, s0[nt][r]);
                ml1 = fmaxf(ml1, s1[nt][r]);
            }
        ml0 = fmaxf(ml0, __shfl_xor(ml0, 16));
        ml0 = fmaxf(ml0, __shfl_xor(ml0, 32));
        ml1 = fmaxf(ml1, __shfl_xor(ml1, 16));
        ml1 = fmaxf(ml1, __shfl_xor(ml1, 32));

        // ---- defer-max: skip rescale when all rows grew < 2^8 ----
        if (!__all((ml0 <= m0 + 8.0f) & (ml1 <= m1 + 8.0f))) {
            float mn0 = fmaxf(m0, ml0), mn1 = fmaxf(m1, ml1);
            float fsc0 = EXP2(m0 - mn0), fsc1 = EXP2(m1 - mn1);
            m0 = mn0; m1 = mn1;
            l0 *= fsc0; l1 *= fsc1;
            float fr0[4], fr1[4];
            #pragma unroll
            for (int r = 0; r < 4; ++r) {
                fr0[r] = __shfl(fsc0, 4 * g + r);
                fr1[r] = __shfl(fsc1, 4 * g + r);
            }
            #pragma unroll
            for (int dt = 0; dt < 8; ++dt)
                #pragma unroll
                for (int r = 0; r < 4; ++r) {
                    O0[dt][r] *= fr0[r];
                    O1[dt][r] *= fr1[r];
                }
        }

        // ---- P = exp2(s - m), pack bf16 (HW cvt_pk) ----
        u32 pk0[4][2], pk1[4][2];
        float ps0 = 0.f, ps1 = 0.f;
        #pragma unroll
        for (int nt = 0; nt < 4; ++nt) {
            float a0 = EXP2(s0[nt][0] - m0), a1 = EXP2(s0[nt][1] - m0);
            float a2 = EXP2(s0[nt][2] - m0), a3 = EXP2(s0[nt][3] - m0);
            ps0 += (a0 + a1) + (a2 + a3);
            pk0[nt][0] = pk2(a0, a1);
            pk0[nt][1] = pk2(a2, a3);
            float c0 = EXP2(s1[nt][0] - m1), c1 = EXP2(s1[nt][1] - m1);
            float c2 = EXP2(s1[nt][2] - m1), c3 = EXP2(s1[nt][3] - m1);
            ps1 += (c0 + c1) + (c2 + c3);
            pk1[nt][0] = pk2(c0, c1);
            pk1[nt][1] = pk2(c2, c3);
        }
        ps0 += __shfl_xor(ps0, 16);
        ps0 += __shfl_xor(ps0, 32);
        ps1 += __shfl_xor(ps1, 16);
        ps1 += __shfl_xor(ps1, 32);
        l0 += ps0; l1 += ps1;

        // ---- PV (verified 8-shfl A-fragment assembly) ----
        const int s0l = l15 | ((2 * (g & 1)) << 4);
        const int s1l = s0l + 16;
        const int hiH = g >> 1;
        #pragma unroll
        for (int kw = 0; kw < 2; ++kw) {
            u32 a0, a1, a2, a3, c0, c1, c2, c3;
            {
                u32 x0 = __shfl(pk0[2 * kw][0], s0l), y0 = __shfl(pk0[2 * kw + 1][0], s0l);
                u32 x1 = __shfl(pk0[2 * kw][1], s0l), y1 = __shfl(pk0[2 * kw + 1][1], s0l);
                u32 x2 = __shfl(pk0[2 * kw][0], s1l), y2 = __shfl(pk0[2 * kw + 1][0], s1l);
                u32 x3 = __shfl(pk0[2 * kw][1], s1l), y3 = __shfl(pk0[2 * kw + 1][1], s1l);
                a0 = hiH ? y0 : x0; a1 = hiH ? y1 : x1;
                a2 = hiH ? y2 : x2; a3 = hiH ? y3 : x3;
            }
            {
                u32 x0 = __shfl(pk1[2 * kw][0], s0l), y0 = __shfl(pk1[2 * kw + 1][0], s0l);
                u32 x1 = __shfl(pk1[2 * kw][1], s0l), y1 = __shfl(pk1[2 * kw + 1][1], s0l);
                u32 x2 = __shfl(pk1[2 * kw][0], s1l), y2 = __shfl(pk1[2 * kw + 1][0], s1l);
                u32 x3 = __shfl(pk1[2 * kw][1], s1l), y3 = __shfl(pk1[2 * kw + 1][1], s1l);
                c0 = hiH ? y0 : x0; c1 = hiH ? y1 : x1;
                c2 = hiH ? y2 : x2; c3 = hiH ? y3 : x3;
            }
            union { u32 w[4]; bf16x8 v; } pa, pb;
            pa.w[0] = a0; pa.w[1] = a1; pa.w[2] = a2; pa.w[3] = a3;
            pb.w[0] = c0; pb.w[1] = c1; pb.w[2] = c2; pb.w[3] = c3;
            __builtin_amdgcn_s_setprio(1);
            #pragma unroll
            for (int dt = 0; dt < 8; ++dt) {
                bf16x8 vf = *(const bf16x8*)(bv + (16 * dt + l15) * 128 + voff[kw]);
                O0[dt] = MFMA16(pa.v, vf, O0[dt]);
                O1[dt] = MFMA16(pb.v, vf, O1[dt]);
            }
            __builtin_amdgcn_s_setprio(0);
        }

        __syncthreads();
        buf ^= 1;
    }

    // ---- epilogue: bf16 unnormalized partials + (m,l); m is log2-domain ----
    u16* op = opart + ((size_t)z * 16384 + q0row) * DH;
    #pragma unroll
    for (int dt = 0; dt < 8; ++dt)
        #pragma unroll
        for (int r = 0; r < 4; ++r) {
            op[(size_t)(4 * g + r) * DH + 16 * dt + l15]      = bf16_rn(O0[dt][r]);
            op[(size_t)(16 + 4 * g + r) * DH + 16 * dt + l15] = bf16_rn(O1[dt][r]);
        }
    if (lane < 16) {
        ml[(size_t)z * 16384 + q0row + lane]      = make_float2(m0, l0);
        ml[(size_t)z * 16384 + q0row + 16 + lane] = make_float2(m1, l1);
    }
}

// ---------------- Kernel 3: merge the 4 kt-partials (m is log2-domain) ----------------
__global__ __launch_bounds__(256) void merge4(
    const u16* __restrict__ op, const float2* __restrict__ ml, float* __restrict__ O)
{
    int row = blockIdx.x * 16 + (threadIdx.x >> 4);
    int dq  = (threadIdx.x & 15) * 8;
    float2 a[4];
    #pragma unroll
    for (int zz = 0; zz < 4; ++zz) a[zz] = ml[(size_t)zz * 16384 + row];
    float M = fmaxf(fmaxf(a[0].x, a[1].x), fmaxf(a[2].x, a[3].x));
    float w[4], den = 0.f;
    #pragma unroll
    for (int zz = 0; zz < 4; ++zz) {
        w[zz] = EXP2(a[zz].x - M);
        den += a[zz].y * w[zz];
    }
    float inv = 1.0f / den;
    float acc[8];
    #pragma unroll
    for (int j = 0; j < 8; ++j) acc[j] = 0.f;
    #pragma unroll
    for (int zz = 0; zz < 4; ++zz) {
        const u16* p = op + ((size_t)zz * 16384 + row) * DH + dq;
        bf16x8 vv = *(const bf16x8*)p;
        #pragma unroll
        for (int j = 0; j < 8; ++j) acc[j] += w[zz] * bf16_f((u16)vv[j]);
    }
    float4 oa, ob;
    oa.x = acc[0] * inv; oa.y = acc[1] * inv; oa.z = acc[2] * inv; oa.w = acc[3] * inv;
    ob.x = acc[4] * inv; ob.y = acc[5] * inv; ob.z = acc[6] * inv; ob.w = acc[7] * inv;
    *(float4*)(O + (size_t)row * DH + dq)     = oa;
    *(float4*)(O + (size_t)row * DH + dq + 4) = ob;
}

extern "C" void kernel_launch(void* const* d_in, const int* in_sizes, int n_in,
                              void* d_out, int out_size, void* d_ws, size_t ws_size,
                              hipStream_t stream) {
    const float* x  = (const float*)d_in[0];
    const float* Wq = (const float*)d_in[1];
    const float* Wk = (const float*)d_in[2];
    const float* Wv = (const float*)d_in[3];
    float* out = (float*)d_out;

    const size_t SZ = (size_t)B_ * S_ * DH;     // 2,097,152 elems (4 MiB bf16 each)
    u16* qhi = (u16*)d_ws;
    u16* qlo = qhi + SZ;
    u16* khi = qlo + SZ;
    u16* klo = khi + SZ;
    u16* vtp = klo + SZ;
    u16* wpk = vtp + SZ;                        // 1.25 MiB staging image
    u16* opart = wpk + 655360;                  // 16 MiB bf16 partials (Z=4)
    float2* mlp = (float2*)((char*)opart + (size_t)4 * 16384 * DH * 2);
    // total = 20.97M + 1.31M + 16.78M + 0.52M = 39.58 MB (proven bound)

    wconv2<<<320, 256, 0, stream>>>(Wq, Wk, Wv, wpk);
    qkv_v8<<<256, 512, 0, stream>>>(x, wpk, qhi, qlo, khi, klo, vtp);
    flash_db<<<256, 512, 0, stream>>>(qhi, qlo, khi, klo, vtp, opart, mlp);
    merge4<<<1024, 256, 0, stream>>>(opart, mlp, out);
}